// Round 4
// baseline (14.424 us; speedup 1.0000x reference)
//
#include <hip/hip_runtime.h>
#include <math.h>

// ---- problem constants ----
// SIZE=(60,270,480); CHANNELS=14; GRIDS: (60,16,16,8),(30,8,8,4),(15,4,4,2)
// IDX_MAX=(60,3,5) -> patch=(1,90,96); PADDING=(0,1,1) -> ppad=(1,92,98)
// t_embed: [64][1][92][98][14] = 8,078,336 f32 ; t_manip: [64][16]

#define N_PATCH 64
#define PPAD_H 92
#define PPAD_W 98
#define CH 14
#define PIX_PER_PATCH (PPAD_H * PPAD_W)          // 9016
#define PIX_PER_CHUNK 256
#define PIX_PER_BLOCK 768
#define BLOCKS_PER_PATCH ((PIX_PER_PATCH + PIX_PER_BLOCK - 1) / PIX_PER_BLOCK)  // 12
#define TOTAL_EMBED (N_PATCH * PIX_PER_PATCH * CH)
#define TOTAL_MANIP (N_PATCH * 16)

__device__ __forceinline__ float lerpf(float a, float b, float f) {
    return a + f * (b - a);
}

__global__ __launch_bounds__(256) void embed_kernel(
    const int* __restrict__ idx,
    const float* __restrict__ g0,
    const float* __restrict__ g1,
    const float* __restrict__ g2,
    float* __restrict__ out)
{
    __shared__ float s_g0[16 * 16 * 8];   // level-0 plane at t=it (identity in T)
    __shared__ float s_g1[8 * 8 * 4];     // level-1, t-lerp pre-applied
    __shared__ float s_g2[4 * 4 * 2];     // level-2, t-lerp pre-applied
    __shared__ int   s_ho0[3][PPAD_H];    // row offset of h0 (elements), -1 => masked
    __shared__ int   s_ho1[3][PPAD_H];
    __shared__ float s_hf [3][PPAD_H];
    __shared__ int   s_wo0[3][PPAD_W];    // col offset of w0 (elements), -1 => masked
    __shared__ int   s_wo1[3][PPAD_W];
    __shared__ float s_wf [3][PPAD_W];
    __shared__ float s_bufA[PIX_PER_CHUNK * CH];  // 14KB double buffer (A)
    __shared__ float s_bufB[PIX_PER_CHUNK * CH];  // 14KB double buffer (B)

    const int tid = threadIdx.x;
    const int n   = blockIdx.y;
    const int it  = idx[3 * n + 0];
    const int ih  = idx[3 * n + 1];
    const int iw  = idx[3 * n + 2];

    // ---- stage level-0 t-plane: 2048 floats = 512 float4 ----
    {
        const float4* src = (const float4*)(g0 + (size_t)it * (16 * 16 * 8));
        float4* dst = (float4*)s_g0;
        for (int i = tid; i < 512; i += 256) dst[i] = src[i];
    }
    // ---- stage level-1 with t-lerp: 256 floats ----
    {
        float xt = ((float)it + 0.5f) * 0.5f - 0.5f;
        float ftf = floorf(xt);
        float ft  = xt - ftf;
        int t0 = (int)ftf;
        int t0c = min(max(t0, 0), 29), t1c = min(t0 + 1, 29);
        const float* p0 = g1 + t0c * (8 * 8 * 4);
        const float* p1 = g1 + t1c * (8 * 8 * 4);
        if (tid < 256) s_g1[tid] = lerpf(p0[tid], p1[tid], ft);
    }
    // ---- stage level-2 with t-lerp: 32 floats ----
    {
        float xt = ((float)it + 0.5f) * 0.25f - 0.5f;
        float ftf = floorf(xt);
        float ft  = xt - ftf;
        int t0 = (int)ftf;
        int t0c = min(max(t0, 0), 14), t1c = min(t0 + 1, 14);
        const float* p0 = g2 + t0c * (4 * 4 * 2);
        const float* p1 = g2 + t1c * (4 * 4 * 2);
        if (tid < 32) s_g2[tid] = lerpf(p0[tid], p1[tid], ft);
    }
    // ---- h LUTs (92 rows x 3 levels) ----
    if (tid < PPAD_H) {
        int rh = ih * 90 + tid - 1;
        bool ok = (unsigned)rh < 270u;
        const int   Hgs[3] = {16, 8, 4};
        const int   rst[3] = {16 * 8, 8 * 4, 4 * 2};
        const float shs[3] = {(float)((double)16 / 270.0),
                              (float)((double)8  / 270.0),
                              (float)((double)4  / 270.0)};
        #pragma unroll
        for (int l = 0; l < 3; ++l) {
            float xh = ((float)rh + 0.5f) * shs[l] - 0.5f;
            float ff = floorf(xh);
            float f  = xh - ff;
            int h0 = (int)ff;
            int h0c = min(max(h0, 0), Hgs[l] - 1);
            int h1c = min(h0 + 1, Hgs[l] - 1);
            s_ho0[l][tid] = ok ? h0c * rst[l] : -1;
            s_ho1[l][tid] = h1c * rst[l];
            s_hf [l][tid] = f;
        }
    }
    // ---- w LUTs (98 cols x 3 levels) ----
    if (tid < PPAD_W) {
        int rw = iw * 96 + tid - 1;
        bool ok = (unsigned)rw < 480u;
        const int   Wgs[3] = {16, 8, 4};
        const int   cst[3] = {8, 4, 2};
        const float sws[3] = {(float)((double)16 / 480.0),
                              (float)((double)8  / 480.0),
                              (float)((double)4  / 480.0)};
        #pragma unroll
        for (int l = 0; l < 3; ++l) {
            float xw = ((float)rw + 0.5f) * sws[l] - 0.5f;
            float ff = floorf(xw);
            float f  = xw - ff;
            int w0 = (int)ff;
            int w0c = min(max(w0, 0), Wgs[l] - 1);
            int w1c = min(w0 + 1, Wgs[l] - 1);
            s_wo0[l][tid] = ok ? w0c * cst[l] : -1;
            s_wo1[l][tid] = w1c * cst[l];
            s_wf [l][tid] = f;
        }
    }

    // ---- fused manip (one block only): 1024 outputs, f64 sin/cos of f32 arg ----
    if (blockIdx.x == 0 && n == 0) {
        float* om = out + TOTAL_EMBED;
        for (int e = tid; e < TOTAL_MANIP; e += 256) {
            int nn = e >> 4;
            int j  = e & 15;
            int l  = j & 7;
            float base = (float)M_PI * (float)(1 << l);  // fl32(2^l*pi), pow2 exact
            float v = (float)idx[3 * nn + 0] * base;     // f32 mul = reference
            double dv = (double)v;
            om[e] = (float)((j < 8) ? sin(dv) : cos(dv));
        }
    }

    const int pstart = blockIdx.x * PIX_PER_BLOCK;
    const int pend   = min(pstart + PIX_PER_BLOCK, PIX_PER_PATCH);
    const int nchunks = (pend - pstart + PIX_PER_CHUNK - 1) / PIX_PER_CHUNK;
    float* outp = out + (size_t)n * PIX_PER_PATCH * CH;

    // compute one chunk of 256 pixels into LDS buffer b2
    auto compute_chunk = [&](int pb, float* __restrict__ b2) {
        int p = pb + tid;
        if (p >= pend) return;
        int hh = p / PPAD_W;
        int ww = p - hh * PPAD_W;
        float2* b = (float2*)(b2 + tid * CH);

        int ho0_0 = s_ho0[0][hh];
        int wo0_0 = s_wo0[0][ww];
        if ((ho0_0 | wo0_0) < 0) {
            float2 z = make_float2(0.f, 0.f);
            b[0] = z; b[1] = z; b[2] = z; b[3] = z; b[4] = z; b[5] = z; b[6] = z;
            return;
        }
        float res[CH];
        // ---- level 0: C=8 ----
        {
            int ho1 = s_ho1[0][hh], wo1 = s_wo1[0][ww];
            float fh = s_hf[0][hh], fw = s_wf[0][ww];
            const float4* c00 = (const float4*)(s_g0 + ho0_0 + wo0_0);
            const float4* c01 = (const float4*)(s_g0 + ho0_0 + wo1);
            const float4* c10 = (const float4*)(s_g0 + ho1 + wo0_0);
            const float4* c11 = (const float4*)(s_g0 + ho1 + wo1);
            #pragma unroll
            for (int q = 0; q < 2; ++q) {
                float4 a = c00[q], bb = c01[q], c = c10[q], d = c11[q];
                res[q * 4 + 0] = lerpf(lerpf(a.x, bb.x, fw), lerpf(c.x, d.x, fw), fh);
                res[q * 4 + 1] = lerpf(lerpf(a.y, bb.y, fw), lerpf(c.y, d.y, fw), fh);
                res[q * 4 + 2] = lerpf(lerpf(a.z, bb.z, fw), lerpf(c.z, d.z, fw), fh);
                res[q * 4 + 3] = lerpf(lerpf(a.w, bb.w, fw), lerpf(c.w, d.w, fw), fh);
            }
        }
        // ---- level 1: C=4 ----
        {
            int ho0 = s_ho0[1][hh], ho1 = s_ho1[1][hh];
            int wo0 = s_wo0[1][ww], wo1 = s_wo1[1][ww];
            float fh = s_hf[1][hh], fw = s_wf[1][ww];
            float4 a = *(const float4*)(s_g1 + ho0 + wo0);
            float4 bb = *(const float4*)(s_g1 + ho0 + wo1);
            float4 c = *(const float4*)(s_g1 + ho1 + wo0);
            float4 d = *(const float4*)(s_g1 + ho1 + wo1);
            res[8]  = lerpf(lerpf(a.x, bb.x, fw), lerpf(c.x, d.x, fw), fh);
            res[9]  = lerpf(lerpf(a.y, bb.y, fw), lerpf(c.y, d.y, fw), fh);
            res[10] = lerpf(lerpf(a.z, bb.z, fw), lerpf(c.z, d.z, fw), fh);
            res[11] = lerpf(lerpf(a.w, bb.w, fw), lerpf(c.w, d.w, fw), fh);
        }
        // ---- level 2: C=2 ----
        {
            int ho0 = s_ho0[2][hh], ho1 = s_ho1[2][hh];
            int wo0 = s_wo0[2][ww], wo1 = s_wo1[2][ww];
            float fh = s_hf[2][hh], fw = s_wf[2][ww];
            float2 a = *(const float2*)(s_g2 + ho0 + wo0);
            float2 bb = *(const float2*)(s_g2 + ho0 + wo1);
            float2 c = *(const float2*)(s_g2 + ho1 + wo0);
            float2 d = *(const float2*)(s_g2 + ho1 + wo1);
            res[12] = lerpf(lerpf(a.x, bb.x, fw), lerpf(c.x, d.x, fw), fh);
            res[13] = lerpf(lerpf(a.y, bb.y, fw), lerpf(c.y, d.y, fw), fh);
        }
        b[0] = make_float2(res[0],  res[1]);
        b[1] = make_float2(res[2],  res[3]);
        b[2] = make_float2(res[4],  res[5]);
        b[3] = make_float2(res[6],  res[7]);
        b[4] = make_float2(res[8],  res[9]);
        b[5] = make_float2(res[10], res[11]);
        b[6] = make_float2(res[12], res[13]);
    };

    // prologue sync also covers the grid/LUT staging above
    compute_chunk(pstart, s_bufA);
    __syncthreads();

    // double-buffered pipeline: store chunk k while computing chunk k+1
    for (int k = 0; k < nchunks; ++k) {
        float* cbuf = (k & 1) ? s_bufB : s_bufA;
        float* nbuf = (k & 1) ? s_bufA : s_bufB;
        int pb  = pstart + k * PIX_PER_CHUNK;
        int cnt = min(PIX_PER_CHUNK, pend - pb);   // even; cnt*14 % 4 == 0

        // ---- store chunk k (issue first: streams while compute runs) ----
        const int nf4 = cnt * CH / 4;
        const float4* sb = (const float4*)cbuf;
        float4* gb = (float4*)(outp + (size_t)pb * CH);
        for (int j = tid; j < nf4; j += 256) gb[j] = sb[j];

        // ---- compute chunk k+1 into the other buffer ----
        if (k + 1 < nchunks) compute_chunk(pb + PIX_PER_CHUNK, nbuf);

        __syncthreads();
    }
}

extern "C" void kernel_launch(void* const* d_in, const int* in_sizes, int n_in,
                              void* d_out, int out_size, void* d_ws, size_t ws_size,
                              hipStream_t stream) {
    const int*   idx = (const int*)  d_in[0];
    const float* g0  = (const float*)d_in[3];
    const float* g1  = (const float*)d_in[4];
    const float* g2  = (const float*)d_in[5];
    float* out = (float*)d_out;

    dim3 grid(BLOCKS_PER_PATCH, N_PATCH);   // (12, 64) = 768 blocks = 3/CU exact
    embed_kernel<<<grid, 256, 0, stream>>>(idx, g0, g1, g2, out);
}